// Round 7
// baseline (524.729 us; speedup 1.0000x reference)
//
#include <hip/hip_runtime.h>

// TGV prox primal-dual, 30 iterations on (3,512,512) fp32.
// 30 dispatches (kernel boundary = cheap cross-XCD barrier; grid.sync measured
// ~160us/iter in round 5 — dead end). State fp32 SoA planes (x2,r0,r1,u0..u3)
// ping-ponged in d_ws (fp16 compression regressed in round 6: body is
// latency-bound, not BW-bound). This round: 512-thread blocks on the same
// 64x16 tile (24 waves/CU vs 12), stage-1 global loads prefetched into
// registers BEFORE the LDS staging phase (overlap latency chains), interior+
// ring unified into one 324-strip task set, stage-2 on all 512 threads.

#define H 512
#define W 512
#define C 3
#define HW (H * W)
#define CHW (C * H * W)
#define N_IT 30

#define TW 64
#define TH 16
#define NTHREADS 512

#define TAU     0.01f
#define LAM2    0.15f
#define RHO     1.99f
#define SIGMA   1.3888888888888888f   /* 1/TAU/72 */
#define INV_TL1 1000.0f               /* 1/(TAU*LAM1) */
#define INV_1PT (1.0f / 1.01f)        /* 1/(1+TAU) */

#define UROWS 20
#define USTR  80
#define BROWS 18
#define BSTR  72
#define NSTRIP 324   /* 18 rows x 18 strips-of-4 covering the +1 ring region */

struct Lds {
    float su[4][UROWS][USTR];
    float sb[3][BROWS][BSTR]; // 0=xbar 1=rbar0 2=rbar1
};

// MODE: 0 = first iter (state synthesized from y), 1 = middle, 2 = last
template <int MODE>
__device__ __forceinline__ void iter_body(const float* __restrict__ y,
                                          const float* __restrict__ src,
                                          float* __restrict__ dst,
                                          Lds& L, int c, int i0, int j0, int tid)
{
    const int cb = c * HW;

    // ---- phase A: prefetch stage-1 strip data (independent of LDS staging) --
    const bool s1act = tid < NSTRIP;
    int s1row = 0, s1col = 0;
    float yv[4], x2c[4], r0c[4], r1c[4];
    if (s1act) {
        s1row = tid / 18 - 1;                 // -1..16
        s1col = (tid - (s1row + 1) * 18) * 4 - 4;  // -4,0,...,64
        const int gi  = i0 + s1row;
        const int gjb = j0 + s1col;
        const bool row_ok = (unsigned)gi < H;
        if (row_ok && gjb >= 0 && gjb + 3 < W) {
            const int p = cb + gi * W + gjb;
            *(float4*)yv = *(const float4*)(y + p);
            if (MODE != 0) {
                *(float4*)x2c = *(const float4*)(src + p);
                *(float4*)r0c = *(const float4*)(src + CHW + p);
                *(float4*)r1c = *(const float4*)(src + 2 * CHW + p);
            }
        } else {
            #pragma unroll
            for (int e = 0; e < 4; ++e) {
                const int gj = gjb + e;
                const bool ok = row_ok && ((unsigned)gj < W);
                const int p = cb + gi * W + gj;
                yv[e] = ok ? y[p] : 0.f;
                if (MODE != 0) {
                    x2c[e] = ok ? src[p] : 0.f;
                    r0c[e] = ok ? src[CHW + p] : 0.f;
                    r1c[e] = ok ? src[2 * CHW + p] : 0.f;
                }
            }
        }
        if (MODE == 0) {
            #pragma unroll
            for (int e = 0; e < 4; ++e) { x2c[e] = yv[e]; r0c[e] = 0.f; r1c[e] = 0.f; }
        }
    }

    // ---- phase B: stage u planes into LDS (+2 halo, coalesced float4) ------
    if (MODE != 0) {
        for (int t = tid; t < 4 * UROWS * 19; t += NTHREADS) {
            const int pl  = t / (UROWS * 19);
            const int rm  = t - pl * (UROWS * 19);
            const int row = rm / 19;
            const int k   = rm - row * 19;
            const int gi  = i0 + row - 2;
            const int gj  = j0 + 4 * k - 8;
            float4 v = make_float4(0.f, 0.f, 0.f, 0.f);
            if ((unsigned)gi < H) {
                const float* p = src + (3 + pl) * CHW + cb + gi * W;
                if (gj >= 0 && gj + 3 < W) {
                    v = *(const float4*)(p + gj);
                } else {
                    float a0 = ((unsigned)(gj + 0) < W) ? p[gj + 0] : 0.f;
                    float a1 = ((unsigned)(gj + 1) < W) ? p[gj + 1] : 0.f;
                    float a2 = ((unsigned)(gj + 2) < W) ? p[gj + 2] : 0.f;
                    float a3 = ((unsigned)(gj + 3) < W) ? p[gj + 3] : 0.f;
                    v = make_float4(a0, a1, a2, a3);
                }
            }
            *(float4*)&L.su[pl][row][4 * k] = v;
        }
        __syncthreads();
    }

    // ---- phase C: stage-1 x/r prox on 324 strips; xbar/rbar -> LDS ---------
    if (s1act) {
        const int rr  = s1row;
        const int s   = s1col;
        const int gi  = i0 + rr;
        const int gjb = j0 + s;

        float t0c[4], t1c[4], t0n[4], t1w[4];
        if (MODE == 0) {
            #pragma unroll
            for (int e = 0; e < 4; ++e) { t0c[e] = t1c[e] = t0n[e] = t1w[e] = 0.f; }
        } else {
            const int lr = rr + 2;
            const int lc = s + 8;
            float4 v;
            float u0n[4], u0c[4], u0s[4], u1n[5], u1c[5], u2r[6], u3n[5], u3c[5];
            v = *(const float4*)&L.su[0][lr - 1][lc]; u0n[0]=v.x; u0n[1]=v.y; u0n[2]=v.z; u0n[3]=v.w;
            v = *(const float4*)&L.su[0][lr    ][lc]; u0c[0]=v.x; u0c[1]=v.y; u0c[2]=v.z; u0c[3]=v.w;
            v = *(const float4*)&L.su[0][lr + 1][lc]; u0s[0]=v.x; u0s[1]=v.y; u0s[2]=v.z; u0s[3]=v.w;
            v = *(const float4*)&L.su[1][lr - 1][lc]; u1n[0]=v.x; u1n[1]=v.y; u1n[2]=v.z; u1n[3]=v.w;
            u1n[4] = L.su[1][lr - 1][lc + 4];
            v = *(const float4*)&L.su[1][lr    ][lc]; u1c[0]=v.x; u1c[1]=v.y; u1c[2]=v.z; u1c[3]=v.w;
            u1c[4] = L.su[1][lr][lc + 4];
            u2r[0] = L.su[2][lr][lc - 1];
            v = *(const float4*)&L.su[2][lr][lc]; u2r[1]=v.x; u2r[2]=v.y; u2r[3]=v.z; u2r[4]=v.w;
            u2r[5] = L.su[2][lr][lc + 4];
            u3n[0] = L.su[3][lr - 1][lc - 1];
            v = *(const float4*)&L.su[3][lr - 1][lc]; u3n[1]=v.x; u3n[2]=v.y; u3n[3]=v.z; u3n[4]=v.w;
            u3c[0] = L.su[3][lr][lc - 1];
            v = *(const float4*)&L.su[3][lr][lc]; u3c[1]=v.x; u3c[2]=v.y; u3c[3]=v.z; u3c[4]=v.w;

            const bool im0 = gi > 0, imHl = gi < H - 1;
            #pragma unroll
            for (int e = 0; e < 4; ++e) {
                const int gj = gjb + e;
                const bool jm0 = gj > 0;
                t0c[e] = TAU * (u0c[e] - u0s[e] + (jm0 ? u1c[e] : 0.f) - u1c[e + 1]);
                t1c[e] = TAU * (u2r[e + 1] - u2r[e + 2] + u3n[e + 1] - (imHl ? u3c[e + 1] : 0.f));
                t0n[e] = im0 ? TAU * (u0n[e] - u0c[e] + (jm0 ? u1n[e] : 0.f) - u1n[e + 1]) : 0.f;
                t1w[e] = jm0 ? TAU * (u2r[e] - u2r[e + 1] + u3n[e] - (imHl ? u3c[e] : 0.f)) : 0.f;
            }
        }

        const bool imH = gi < H - 1;
        float xnew[4], rn0[4], rn1[4], xb[4], rb0[4], rb1[4];
        #pragma unroll
        for (int e = 0; e < 4; ++e) {
            const int gj = gjb + e;
            const bool jmW = gj < W - 1;
            const float nT  = t0n[e] - (imH ? t0c[e] : 0.f) + t1w[e] - (jmW ? t1c[e] : 0.f);
            const float xv  = (x2c[e] - nT + TAU * yv[e]) * INV_1PT;
            xb[e] = 2.f * xv - x2c[e];
            const float rp0 = r0c[e] + t0c[e];
            const float rp1 = r1c[e] + t1c[e];
            const float nrm = sqrtf(rp0 * rp0 + rp1 * rp1);
            const float f   = 1.f - 1.f / fmaxf(nrm * INV_TL1, 1.f);
            const float rv0 = rp0 * f, rv1 = rp1 * f;
            rb0[e]  = 2.f * rv0 - r0c[e];
            rb1[e]  = 2.f * rv1 - r1c[e];
            xnew[e] = x2c[e] + RHO * (xv - x2c[e]);
            rn0[e]  = r0c[e] + RHO * (rv0 - r0c[e]);
            rn1[e]  = r1c[e] + RHO * (rv1 - r1c[e]);
        }
        *(float4*)&L.sb[0][rr + 1][s + 4] = *(float4*)xb;
        *(float4*)&L.sb[1][rr + 1][s + 4] = *(float4*)rb0;
        *(float4*)&L.sb[2][rr + 1][s + 4] = *(float4*)rb1;

        if (rr >= 0 && rr < TH && s >= 0 && s < TW) {   // interior -> state write
            const int p = cb + gi * W + gjb;
            if (MODE == 2) {
                *(float4*)(dst + p) = *(float4*)xnew;
                *(float4*)(dst + CHW + 2 * p)     = make_float4(rn0[0], rn1[0], rn0[1], rn1[1]);
                *(float4*)(dst + CHW + 2 * p + 4) = make_float4(rn0[2], rn1[2], rn0[3], rn1[3]);
            } else {
                *(float4*)(dst + p)           = *(float4*)xnew;
                *(float4*)(dst + CHW + p)     = *(float4*)rn0;
                *(float4*)(dst + 2 * CHW + p) = *(float4*)rn1;
            }
        }
    }
    __syncthreads();

    // ---- phase D: stage-2 u prox, 2 px per thread (all 512 threads) --------
    {
        const int tx = tid & 31, ty = tid >> 5;
        const int gi  = i0 + ty;
        const int gjb = j0 + 2 * tx;
        const int lr  = ty + 1;
        const int lc  = 2 * tx + 4;

        float xA[4], xS[4], xN[2], r0C[3], r0N[2], r1C[3], r1S[2];
        xA[0] = L.sb[0][lr][lc - 1]; xA[1] = L.sb[0][lr][lc];
        xA[2] = L.sb[0][lr][lc + 1]; xA[3] = L.sb[0][lr][lc + 2];
        xS[0] = L.sb[0][lr + 1][lc - 1]; xS[1] = L.sb[0][lr + 1][lc];
        xS[2] = L.sb[0][lr + 1][lc + 1]; xS[3] = L.sb[0][lr + 1][lc + 2];
        xN[0] = L.sb[0][lr - 1][lc]; xN[1] = L.sb[0][lr - 1][lc + 1];
        r0C[0] = L.sb[1][lr][lc - 1]; r0C[1] = L.sb[1][lr][lc]; r0C[2] = L.sb[1][lr][lc + 1];
        r0N[0] = L.sb[1][lr - 1][lc]; r0N[1] = L.sb[1][lr - 1][lc + 1];
        r1C[0] = L.sb[2][lr][lc - 1]; r1C[1] = L.sb[2][lr][lc]; r1C[2] = L.sb[2][lr][lc + 1];
        r1S[0] = L.sb[2][lr + 1][lc]; r1S[1] = L.sb[2][lr + 1][lc + 1];

        float u0o[2], u1o[2], u2o[2], u3o[2];
        if (MODE == 0) {
            u0o[0]=u0o[1]=u1o[0]=u1o[1]=u2o[0]=u2o[1]=u3o[0]=u3o[1]=0.f;
        } else {
            const int lru = ty + 2, lcu = 2 * tx + 8;
            float2 v;
            v = *(const float2*)&L.su[0][lru][lcu]; u0o[0]=v.x; u0o[1]=v.y;
            v = *(const float2*)&L.su[1][lru][lcu]; u1o[0]=v.x; u1o[1]=v.y;
            v = *(const float2*)&L.su[2][lru][lcu]; u2o[0]=v.x; u2o[1]=v.y;
            v = *(const float2*)&L.su[3][lru][lcu]; u3o[0]=v.x; u3o[1]=v.y;
        }

        const bool im0 = gi > 0, imH = gi < H - 1;
        float un0[2], un1[2], un2[2], un3[2];
        #pragma unroll
        for (int e = 0; e < 2; ++e) {
            const int gj = gjb + e;
            const bool jm0 = gj > 0, jmW = gj < W - 1;
            const float xC = xA[e + 1], xE = xA[e + 2], xW_ = xA[e];
            const float I0c = (imH ? xS[e + 1] - xC : 0.f) - r0C[e + 1];
            const float I0n = im0 ? (xC - xN[e] - r0N[e]) : 0.f;
            const float I0w = jm0 ? ((imH ? xS[e] - xW_ : 0.f) - r0C[e]) : 0.f;
            const float I1c = (jmW ? xE - xC : 0.f) - r1C[e + 1];
            const float I1w = jm0 ? (xC - xW_ - r1C[e]) : 0.f;
            const float I1s = imH ? ((jmW ? xS[e + 2] - xS[e + 1] : 0.f) - r1S[e]) : 0.f;
            const float g0 = I0c - I0n;
            const float g1 = jm0 ? (I0c - I0w) : 0.f;
            const float g2 = I1c - I1w;
            const float g3 = imH ? (I1s - I1c) : 0.f;
            const float up0 = u0o[e] + SIGMA * g0;
            const float up1 = u1o[e] + SIGMA * g1;
            const float up2 = u2o[e] + SIGMA * g2;
            const float up3 = u3o[e] + SIGMA * g3;
            const float nrm = sqrtf(up0 * up0 + up1 * up1 + up2 * up2 + up3 * up3);
            const float inv = 1.f / fmaxf(nrm * (1.0f / LAM2), 1.f);
            un0[e] = u0o[e] + RHO * (up0 * inv - u0o[e]);
            un1[e] = u1o[e] + RHO * (up1 * inv - u1o[e]);
            un2[e] = u2o[e] + RHO * (up2 * inv - u2o[e]);
            un3[e] = u3o[e] + RHO * (up3 * inv - u3o[e]);
        }
        const int p = cb + gi * W + gjb;
        if (MODE == 2) {
            #pragma unroll
            for (int e = 0; e < 2; ++e)
                *(float4*)(dst + 3 * CHW + 4 * (p + e)) =
                    make_float4(un0[e], un1[e], un2[e], un3[e]);
        } else {
            *(float2*)(dst + 3 * CHW + p) = make_float2(un0[0], un0[1]);
            *(float2*)(dst + 4 * CHW + p) = make_float2(un1[0], un1[1]);
            *(float2*)(dst + 5 * CHW + p) = make_float2(un2[0], un2[1]);
            *(float2*)(dst + 6 * CHW + p) = make_float2(un3[0], un3[1]);
        }
    }
}

template <int MODE>
__global__ __launch_bounds__(NTHREADS)
void fused_it(const float* __restrict__ y,
              const float* __restrict__ src,
              float* __restrict__ dst)
{
    __shared__ Lds L;
    iter_body<MODE>(y, src, dst, L,
                    blockIdx.z, blockIdx.y * TH, blockIdx.x * TW, threadIdx.x);
}

extern "C" void kernel_launch(void* const* d_in, const int* in_sizes, int n_in,
                              void* d_out, int out_size, void* d_ws, size_t ws_size,
                              hipStream_t stream) {
    const float* y = (const float*)d_in[0];
    float* out  = (float*)d_out;
    float* buf0 = (float*)d_ws;
    float* buf1 = buf0 + 7 * CHW;   // 2 x 7 fp32 planes = 44 MB, ws ~256 MB

    dim3 blk(NTHREADS, 1, 1);
    dim3 grd(W / TW, H / TH, C);    // (8, 32, 3) = 768 blocks = 3/CU

    // iter 1: state0 = (y,0,0) synthesized, writes buf0
    fused_it<0><<<grd, blk, 0, stream>>>(y, buf0 /*unused*/, buf0);
    // iters 2..29 alternate buf0 <-> buf1
    for (int k = 2; k < N_IT; ++k) {
        float* s = (k % 2 == 0) ? buf0 : buf1;
        float* d = (k % 2 == 0) ? buf1 : buf0;
        fused_it<1><<<grd, blk, 0, stream>>>(y, s, d);
    }
    // iter 30 reads buf0 (written by iter 29), writes d_out interleaved
    fused_it<2><<<grd, blk, 0, stream>>>(y, buf0, out);
}

// Round 8
// 479.327 us; speedup vs baseline: 1.0947x; 1.0947x over previous
//
#include <hip/hip_runtime.h>

// TGV prox primal-dual, 30 iterations on (3,512,512) fp32.
// Round-3 verified body (435us) + ONE change: XCD-pinned tile swizzle.
// HW assigns blockIdx.x % 8 -> XCD round-robin; we permute block->tile so
// XCD x owns a contiguous 96-tile slab (channel c, 12 tile-rows). The slab's
// state (2.75 MB) was written by the SAME XCD last dispatch -> dirty-line L2
// reuse across the 30 dispatches instead of a full 22 MB L3 round-trip/iter.
// State fp32 SoA planes (x2,r0,r1,u0..u3) ping-ponged in d_ws; iter 1
// specialized (state=(y,0,0)); iter 30 writes d_out interleaved.
// Per-block: 64x16 tile, 256 threads, u staged to LDS (+2 halo), stage-1
// (x/r prox -> xbar/rbar in LDS) on +1 ring, stage-2 (u prox) on interior.

#define H 512
#define W 512
#define C 3
#define HW (H * W)
#define CHW (C * H * W)
#define N_IT 30

#define TW 64
#define TH 16

#define TAU     0.01f
#define LAM2    0.15f
#define RHO     1.99f
#define SIGMA   1.3888888888888888f   /* 1/TAU/72 */
#define INV_TL1 1000.0f               /* 1/(TAU*LAM1) */
#define INV_1PT (1.0f / 1.01f)        /* 1/(1+TAU) */

#define UROWS 20
#define USTR  80
#define BROWS 18
#define BSTR  72

struct Lds {
    float su[4][UROWS][USTR];
    float sb[3][BROWS][BSTR]; // 0=xbar 1=rbar0 2=rbar1
};

// MODE: 0 = first iter (state synthesized), 1 = middle, 2 = last (interleaved out)
template <int MODE>
__device__ __forceinline__ void iter_body(const float* __restrict__ y,
                                          const float* __restrict__ src,
                                          float* __restrict__ dst,
                                          Lds& L, int c, int i0, int j0, int tid)
{
    const int cb = c * HW;

    // ---- stage u planes into LDS (coalesced float4, masked at image edges) ----
    if (MODE != 0) {
        for (int t = tid; t < 4 * UROWS * 19; t += 256) {
            const int pl  = t / (UROWS * 19);
            const int rm  = t - pl * (UROWS * 19);
            const int row = rm / 19;
            const int k   = rm - row * 19;
            const int gi  = i0 + row - 2;
            const int gj  = j0 + 4 * k - 8;
            float4 v = make_float4(0.f, 0.f, 0.f, 0.f);
            if ((unsigned)gi < H) {
                const float* p = src + (3 + pl) * CHW + cb + gi * W;
                if (gj >= 0 && gj + 3 < W) {
                    v = *(const float4*)(p + gj);
                } else {
                    float a0 = ((unsigned)(gj + 0) < W) ? p[gj + 0] : 0.f;
                    float a1 = ((unsigned)(gj + 1) < W) ? p[gj + 1] : 0.f;
                    float a2 = ((unsigned)(gj + 2) < W) ? p[gj + 2] : 0.f;
                    float a3 = ((unsigned)(gj + 3) < W) ? p[gj + 3] : 0.f;
                    v = make_float4(a0, a1, a2, a3);
                }
            }
            *(float4*)&L.su[pl][row][4 * k] = v;
        }
        __syncthreads();
    }

    // ---- stage 1: x/r prox on a strip of 4 positions; xbar/rbar -> LDS ----
    auto strip1 = [&](int rr, int s, bool interior) {
        const int gi  = i0 + rr;
        const int gjb = j0 + s;
        const bool row_ok = (unsigned)gi < H;

        float yv[4], x2c[4], r0c[4], r1c[4];
        if (row_ok && gjb >= 0 && gjb + 3 < W) {
            const int p = cb + gi * W + gjb;
            *(float4*)yv = *(const float4*)(y + p);
            if (MODE != 0) {
                *(float4*)x2c = *(const float4*)(src + p);
                *(float4*)r0c = *(const float4*)(src + CHW + p);
                *(float4*)r1c = *(const float4*)(src + 2 * CHW + p);
            }
        } else {
            #pragma unroll
            for (int e = 0; e < 4; ++e) {
                const int gj = gjb + e;
                const bool ok = row_ok && ((unsigned)gj < W);
                const int p = cb + gi * W + gj;
                yv[e] = ok ? y[p] : 0.f;
                if (MODE != 0) {
                    x2c[e] = ok ? src[p] : 0.f;
                    r0c[e] = ok ? src[CHW + p] : 0.f;
                    r1c[e] = ok ? src[2 * CHW + p] : 0.f;
                }
            }
        }
        if (MODE == 0) {
            #pragma unroll
            for (int e = 0; e < 4; ++e) { x2c[e] = yv[e]; r0c[e] = 0.f; r1c[e] = 0.f; }
        }

        float t0c[4], t1c[4], t0n[4], t1w[4];
        if (MODE == 0) {
            #pragma unroll
            for (int e = 0; e < 4; ++e) { t0c[e] = t1c[e] = t0n[e] = t1w[e] = 0.f; }
        } else {
            const int lr = rr + 2;
            const int lc = s + 8;
            float4 v;
            float u0n[4], u0c[4], u0s[4], u1n[5], u1c[5], u2r[6], u3n[5], u3c[5];
            v = *(const float4*)&L.su[0][lr - 1][lc]; u0n[0]=v.x; u0n[1]=v.y; u0n[2]=v.z; u0n[3]=v.w;
            v = *(const float4*)&L.su[0][lr    ][lc]; u0c[0]=v.x; u0c[1]=v.y; u0c[2]=v.z; u0c[3]=v.w;
            v = *(const float4*)&L.su[0][lr + 1][lc]; u0s[0]=v.x; u0s[1]=v.y; u0s[2]=v.z; u0s[3]=v.w;
            v = *(const float4*)&L.su[1][lr - 1][lc]; u1n[0]=v.x; u1n[1]=v.y; u1n[2]=v.z; u1n[3]=v.w;
            u1n[4] = L.su[1][lr - 1][lc + 4];
            v = *(const float4*)&L.su[1][lr    ][lc]; u1c[0]=v.x; u1c[1]=v.y; u1c[2]=v.z; u1c[3]=v.w;
            u1c[4] = L.su[1][lr][lc + 4];
            u2r[0] = L.su[2][lr][lc - 1];
            v = *(const float4*)&L.su[2][lr][lc]; u2r[1]=v.x; u2r[2]=v.y; u2r[3]=v.z; u2r[4]=v.w;
            u2r[5] = L.su[2][lr][lc + 4];
            u3n[0] = L.su[3][lr - 1][lc - 1];
            v = *(const float4*)&L.su[3][lr - 1][lc]; u3n[1]=v.x; u3n[2]=v.y; u3n[3]=v.z; u3n[4]=v.w;
            u3c[0] = L.su[3][lr][lc - 1];
            v = *(const float4*)&L.su[3][lr][lc]; u3c[1]=v.x; u3c[2]=v.y; u3c[3]=v.z; u3c[4]=v.w;

            const bool im0 = gi > 0, imHl = gi < H - 1;
            #pragma unroll
            for (int e = 0; e < 4; ++e) {
                const int gj = gjb + e;
                const bool jm0 = gj > 0;
                t0c[e] = TAU * (u0c[e] - u0s[e] + (jm0 ? u1c[e] : 0.f) - u1c[e + 1]);
                t1c[e] = TAU * (u2r[e + 1] - u2r[e + 2] + u3n[e + 1] - (imHl ? u3c[e + 1] : 0.f));
                t0n[e] = im0 ? TAU * (u0n[e] - u0c[e] + (jm0 ? u1n[e] : 0.f) - u1n[e + 1]) : 0.f;
                t1w[e] = jm0 ? TAU * (u2r[e] - u2r[e + 1] + u3n[e] - (imHl ? u3c[e] : 0.f)) : 0.f;
            }
        }

        const bool imH = gi < H - 1;
        float xnew[4], rn0[4], rn1[4], xb[4], rb0[4], rb1[4];
        #pragma unroll
        for (int e = 0; e < 4; ++e) {
            const int gj = gjb + e;
            const bool jmW = gj < W - 1;
            const float nT  = t0n[e] - (imH ? t0c[e] : 0.f) + t1w[e] - (jmW ? t1c[e] : 0.f);
            const float xv  = (x2c[e] - nT + TAU * yv[e]) * INV_1PT;
            xb[e] = 2.f * xv - x2c[e];
            const float rp0 = r0c[e] + t0c[e];
            const float rp1 = r1c[e] + t1c[e];
            const float nrm = sqrtf(rp0 * rp0 + rp1 * rp1);
            const float f   = 1.f - 1.f / fmaxf(nrm * INV_TL1, 1.f);
            const float rv0 = rp0 * f, rv1 = rp1 * f;
            rb0[e]  = 2.f * rv0 - r0c[e];
            rb1[e]  = 2.f * rv1 - r1c[e];
            xnew[e] = x2c[e] + RHO * (xv - x2c[e]);
            rn0[e]  = r0c[e] + RHO * (rv0 - r0c[e]);
            rn1[e]  = r1c[e] + RHO * (rv1 - r1c[e]);
        }
        *(float4*)&L.sb[0][rr + 1][s + 4] = *(float4*)xb;
        *(float4*)&L.sb[1][rr + 1][s + 4] = *(float4*)rb0;
        *(float4*)&L.sb[2][rr + 1][s + 4] = *(float4*)rb1;

        if (interior) {
            const int p = cb + gi * W + gjb;
            if (MODE == 2) {
                *(float4*)(dst + p) = *(float4*)xnew;
                *(float4*)(dst + CHW + 2 * p)     = make_float4(rn0[0], rn1[0], rn0[1], rn1[1]);
                *(float4*)(dst + CHW + 2 * p + 4) = make_float4(rn0[2], rn1[2], rn0[3], rn1[3]);
            } else {
                *(float4*)(dst + p)           = *(float4*)xnew;
                *(float4*)(dst + CHW + p)     = *(float4*)rn0;
                *(float4*)(dst + 2 * CHW + p) = *(float4*)rn1;
            }
        }
    };

    { // pass 1: interior 16 rows x 16 strips
        const int ty = tid >> 4, tx = tid & 15;
        strip1(ty, 4 * tx, true);
    }
    if (tid < 68) { // pass 2: +1 ring strips
        int rr, s;
        if (tid < 18)      { rr = -1;       s = 4 * tid - 4; }
        else if (tid < 36) { rr = TH;       s = 4 * (tid - 18) - 4; }
        else if (tid < 52) { rr = tid - 36; s = -4; }
        else               { rr = tid - 52; s = TW; }
        strip1(rr, s, false);
    }
    __syncthreads();

    // ---- stage 2: u prox on interior, xbar/rbar from LDS ----
    {
        const int tx = tid & 15, ty = tid >> 4;
        const int gi  = i0 + ty;
        const int gjb = j0 + 4 * tx;
        const int lr  = ty + 1;
        const int lc  = 4 * tx + 4;
        float4 v;
        float xA[6], xS[6], xN[4], r0C[5], r0N[4], r1C[5], r1S[4];
        xA[0] = L.sb[0][lr][lc - 1];
        v = *(const float4*)&L.sb[0][lr][lc]; xA[1]=v.x; xA[2]=v.y; xA[3]=v.z; xA[4]=v.w;
        xA[5] = L.sb[0][lr][lc + 4];
        xS[0] = L.sb[0][lr + 1][lc - 1];
        v = *(const float4*)&L.sb[0][lr + 1][lc]; xS[1]=v.x; xS[2]=v.y; xS[3]=v.z; xS[4]=v.w;
        xS[5] = L.sb[0][lr + 1][lc + 4];
        v = *(const float4*)&L.sb[0][lr - 1][lc]; xN[0]=v.x; xN[1]=v.y; xN[2]=v.z; xN[3]=v.w;
        r0C[0] = L.sb[1][lr][lc - 1];
        v = *(const float4*)&L.sb[1][lr][lc]; r0C[1]=v.x; r0C[2]=v.y; r0C[3]=v.z; r0C[4]=v.w;
        v = *(const float4*)&L.sb[1][lr - 1][lc]; r0N[0]=v.x; r0N[1]=v.y; r0N[2]=v.z; r0N[3]=v.w;
        r1C[0] = L.sb[2][lr][lc - 1];
        v = *(const float4*)&L.sb[2][lr][lc]; r1C[1]=v.x; r1C[2]=v.y; r1C[3]=v.z; r1C[4]=v.w;
        v = *(const float4*)&L.sb[2][lr + 1][lc]; r1S[0]=v.x; r1S[1]=v.y; r1S[2]=v.z; r1S[3]=v.w;

        float u0o[4], u1o[4], u2o[4], u3o[4];
        if (MODE == 0) {
            #pragma unroll
            for (int e = 0; e < 4; ++e) { u0o[e] = u1o[e] = u2o[e] = u3o[e] = 0.f; }
        } else {
            const int lru = ty + 2, lcu = 4 * tx + 8;
            v = *(const float4*)&L.su[0][lru][lcu]; u0o[0]=v.x; u0o[1]=v.y; u0o[2]=v.z; u0o[3]=v.w;
            v = *(const float4*)&L.su[1][lru][lcu]; u1o[0]=v.x; u1o[1]=v.y; u1o[2]=v.z; u1o[3]=v.w;
            v = *(const float4*)&L.su[2][lru][lcu]; u2o[0]=v.x; u2o[1]=v.y; u2o[2]=v.z; u2o[3]=v.w;
            v = *(const float4*)&L.su[3][lru][lcu]; u3o[0]=v.x; u3o[1]=v.y; u3o[2]=v.z; u3o[3]=v.w;
        }

        const bool im0 = gi > 0, imH = gi < H - 1;
        float un0[4], un1[4], un2[4], un3[4];
        #pragma unroll
        for (int e = 0; e < 4; ++e) {
            const int gj = gjb + e;
            const bool jm0 = gj > 0, jmW = gj < W - 1;
            const float xC = xA[e + 1], xE = xA[e + 2], xW_ = xA[e];
            const float I0c = (imH ? xS[e + 1] - xC : 0.f) - r0C[e + 1];
            const float I0n = im0 ? (xC - xN[e] - r0N[e]) : 0.f;
            const float I0w = jm0 ? ((imH ? xS[e] - xW_ : 0.f) - r0C[e]) : 0.f;
            const float I1c = (jmW ? xE - xC : 0.f) - r1C[e + 1];
            const float I1w = jm0 ? (xC - xW_ - r1C[e]) : 0.f;
            const float I1s = imH ? ((jmW ? xS[e + 2] - xS[e + 1] : 0.f) - r1S[e]) : 0.f;
            const float g0 = I0c - I0n;
            const float g1 = jm0 ? (I0c - I0w) : 0.f;
            const float g2 = I1c - I1w;
            const float g3 = imH ? (I1s - I1c) : 0.f;
            const float up0 = u0o[e] + SIGMA * g0;
            const float up1 = u1o[e] + SIGMA * g1;
            const float up2 = u2o[e] + SIGMA * g2;
            const float up3 = u3o[e] + SIGMA * g3;
            const float nrm = sqrtf(up0 * up0 + up1 * up1 + up2 * up2 + up3 * up3);
            const float inv = 1.f / fmaxf(nrm * (1.0f / LAM2), 1.f);
            un0[e] = u0o[e] + RHO * (up0 * inv - u0o[e]);
            un1[e] = u1o[e] + RHO * (up1 * inv - u1o[e]);
            un2[e] = u2o[e] + RHO * (up2 * inv - u2o[e]);
            un3[e] = u3o[e] + RHO * (up3 * inv - u3o[e]);
        }
        const int p = cb + gi * W + gjb;
        if (MODE == 2) {
            #pragma unroll
            for (int e = 0; e < 4; ++e)
                *(float4*)(dst + 3 * CHW + 4 * (p + e)) =
                    make_float4(un0[e], un1[e], un2[e], un3[e]);
        } else {
            *(float4*)(dst + 3 * CHW + p) = *(float4*)un0;
            *(float4*)(dst + 4 * CHW + p) = *(float4*)un1;
            *(float4*)(dst + 5 * CHW + p) = *(float4*)un2;
            *(float4*)(dst + 6 * CHW + p) = *(float4*)un3;
        }
    }
}

template <int MODE>
__global__ __launch_bounds__(256)
void fused_it(const float* __restrict__ y,
              const float* __restrict__ src,
              float* __restrict__ dst)
{
    __shared__ Lds L;
    // XCD-pinned tile swizzle: HW maps blockIdx.x % 8 -> XCD (round-robin).
    // XCD x owns tiles t = x*96 .. x*96+95 = one channel's 12-tile-row slab.
    // Same tile -> same XCD on every one of the 30 dispatches -> the slab's
    // 2.75 MB state written last iter is still dirty in this XCD's 4 MB L2.
    const int b   = blockIdx.x;
    const int t   = (b & 7) * 96 + (b >> 3);
    const int c   = t >> 8;
    const int rem = t & 255;
    iter_body<MODE>(y, src, dst, L,
                    c, (rem >> 3) * TH, (rem & 7) * TW, threadIdx.x);
}

extern "C" void kernel_launch(void* const* d_in, const int* in_sizes, int n_in,
                              void* d_out, int out_size, void* d_ws, size_t ws_size,
                              hipStream_t stream) {
    const float* y = (const float*)d_in[0];
    float* out  = (float*)d_out;
    float* buf0 = (float*)d_ws;
    float* buf1 = buf0 + 7 * CHW;   // 2 x 7 fp32 planes = 44 MB, ws ~256 MB

    dim3 blk(256, 1, 1);
    dim3 grd(768, 1, 1);            // 1-D so the %8 XCD swizzle is explicit

    // iter 1: state0 = (y,0,0) synthesized, writes buf0
    fused_it<0><<<grd, blk, 0, stream>>>(y, buf0 /*unused*/, buf0);
    // iters 2..29 alternate buf0 <-> buf1
    for (int k = 2; k < N_IT; ++k) {
        float* s = (k % 2 == 0) ? buf0 : buf1;
        float* d = (k % 2 == 0) ? buf1 : buf0;
        fused_it<1><<<grd, blk, 0, stream>>>(y, s, d);
    }
    // iter 30 reads buf0 (written by iter 29), writes d_out interleaved
    fused_it<2><<<grd, blk, 0, stream>>>(y, buf0, out);
}